// Round 7
// baseline (474.735 us; speedup 1.0000x reference)
//
#include <hip/hip_runtime.h>

// scatter_mean over SORTED index: E edges x D=128 -> N segments, fp32.
// Edge-streaming walkers: each 64-lane wave owns a segment-aligned window of
// ~EPW edges. Lane l owns float2 column l (64 x 8B = 512B/row, perfectly
// sequential). Wave walks its edges in order; segment id is wave-uniform, so
// on segment change it writes the mean row directly -- no shuffles, no
// atomics, no LDS, no workspace. Bounds: two parallel half-wave binary
// searches per window (2 searches per ~80 edges). Empty segments get
// zero-rows via the rare gap path; walker 0 zeroes the leading gap.

#define EPW 80    // edges per walker window (pre-alignment)
#define D2  64    // float2 per row (D=128)

__global__ __launch_bounds__(256) void scatter_mean_stream(
        const float2* __restrict__ x2,
        const int*    __restrict__ index,
        float2*       __restrict__ out2,
        int E, int N, int W) {
    const int gwave = (int)((blockIdx.x * blockDim.x + threadIdx.x) >> 6);
    if (gwave >= W) return;
    const int l   = threadIdx.x & 63;
    const int sub = l >> 5;   // 0: search s_w ; 1: search s_{w+1}

    // window-defining segments: s_w = index[w*EPW] (sentinel N past the end)
    int pe = (gwave + sub) * EPW;
    int starget = (pe < E) ? index[pe] : N;     // uniform per half-wave
    // lower_bound(index, starget)
    int lo = 0, hi = E;
    while (lo < hi) {
        int mid = (lo + hi) >> 1;
        if (index[mid] < starget) lo = mid + 1; else hi = mid;
    }
    int e     = __shfl(lo, 0, 64);       // first edge of window
    int e_end = __shfl(lo, 32, 64);      // one past last edge
    int s_lo  = __shfl(starget, 0, 64);  // first segment of window
    int s_hi  = __shfl(starget, 32, 64); // first segment of next window

    const float2 z = make_float2(0.f, 0.f);

    // leading global gap: segments [0, s_0) are empty
    if (gwave == 0) {
        for (int g = 0; g < s_lo; ++g) out2[(size_t)g * D2 + l] = z;
    }
    if (e >= e_end) return;   // window swallowed by a long segment

    int   cur = s_lo;
    int   cnt = 0;
    float2 acc = z;
    for (; e < e_end; ++e) {
        int seg = index[e];              // wave-uniform (broadcast load)
        if (seg != cur) {                // wave-uniform branch
            float inv = 1.0f / (float)cnt;
            out2[(size_t)cur * D2 + l] = make_float2(acc.x * inv, acc.y * inv);
            for (int g = cur + 1; g < seg; ++g)        // rare: empty segments
                out2[(size_t)g * D2 + l] = z;
            cur = seg; acc = z; cnt = 0;
        }
        float2 v = x2[(size_t)e * D2 + l];
        acc.x += v.x; acc.y += v.y; ++cnt;
    }
    float inv = 1.0f / (float)cnt;
    out2[(size_t)cur * D2 + l] = make_float2(acc.x * inv, acc.y * inv);
    for (int g = cur + 1; g < s_hi; ++g)               // trailing empty gap
        out2[(size_t)g * D2 + l] = z;
}

extern "C" void kernel_launch(void* const* d_in, const int* in_sizes, int n_in,
                              void* d_out, int out_size, void* d_ws, size_t ws_size,
                              hipStream_t stream) {
    const float* x     = (const float*)d_in[0];
    const int*   index = (const int*)d_in[1];

    const int E = in_sizes[1];            // 640000
    const int N = out_size / 128;         // 100000

    const int W = (E + EPW - 1) / EPW;    // 8000 walkers
    const int threads = 256;              // 4 walkers per block
    const int blocks  = (W * 64 + threads - 1) / threads;   // 2000 blocks
    scatter_mean_stream<<<blocks, threads, 0, stream>>>(
        (const float2*)x, index, (float2*)d_out, E, N, W);
}